// Round 17
// baseline (282.169 us; speedup 1.0000x reference)
//
#include <hip/hip_runtime.h>
#include <cstdint>

#define TSIZE (1u << 19)
#define MASKU (TSIZE - 1u)
#define P1U 2654435761u

// r17: per-XCD partitioned scatter (r15) + parent-block compacted main with
// 2 points/thread average (latency lever: r16 main was 45% VALUBusy at 60%
// occupancy with ~2 active waves/block -> halve waves, double per-thread work).
//  - block = one 32-px parent (4 contiguous children); prefix over 32
//    (child,part) counts; LDS slot->bin map; thread processes tid+256*rep.
//  - records AoS float4 (r11 A/B); NO nontemporal (r13); ws = 1 GiB (r14).
#define CBINS_X 128
#define NCHILD (CBINS_X * CBINS_X)      // 16384 children (16-px bins)
#define NPAR (NCHILD / 4)               // 4096 parents (32-px)
#define XPART 8
#define CAPX 32
#define SLOTS (XPART * NCHILD * CAPX)   // 4,194,304 slots (67 MB recs)

// ---------------- embed core (numerics FROZEN since round 2) ----------------
// RES[15] = 2047 (verified round 2). Levels 0-11 direct (fused 16B pair
// gathers); 12-15 hash; reference searchsorted == identity lookup.
// MLP structure: all 40 gathers issued before any lerp.
__device__ __forceinline__ void embed_point(float2 xv, int orig,
                                            const float* __restrict__ tables,
                                            float* __restrict__ out) {
  constexpr int RESV[16] = {16, 22, 30, 42, 58, 80, 111, 153,
                            212, 294, 406, 561, 776, 1072, 1482, 2047};
  const float2* tabs = reinterpret_cast<const float2*>(tables);

  float4 lo[12], hi[12];
  float2 eh[4][4];
  float w0a[16], w1a[16];

#pragma unroll
  for (int l = 0; l < 12; ++l) {
    const int res = RESV[l];
    const float gs = (float)(2048.0 / (double)res);  // f32(double(2048/res))
    float f0 = floorf(xv.x / gs);
    float f1 = floorf(xv.y / gs);
    float g0 = f0 * gs;
    float g1 = f1 * gs;
    w0a[l] = (xv.x - g0) / ((g0 + gs) - g0);
    w1a[l] = (xv.y - g1) / ((g1 + gs) - g1);
    int base = (int)f0 * res + (int)f1;
    const float2* tab = tabs + (size_t)l * TSIZE;
    lo[l] = *reinterpret_cast<const float4*>(tab + base);
    hi[l] = *reinterpret_cast<const float4*>(tab + base + res);
  }
#pragma unroll
  for (int l = 0; l < 4; ++l) {
    const int res = RESV[12 + l];
    const float gs = (float)(2048.0 / (double)res);
    float f0 = floorf(xv.x / gs);
    float f1 = floorf(xv.y / gs);
    float g0 = f0 * gs;
    float g1 = f1 * gs;
    w0a[12 + l] = (xv.x - g0) / ((g0 + gs) - g0);
    w1a[12 + l] = (xv.y - g1) / ((g1 + gs) - g1);
    uint32_t u0 = (uint32_t)(int)f0;
    uint32_t u1m = (uint32_t)(int)f1 * P1U;
    const float2* tab = tabs + (size_t)(12 + l) * TSIZE;
    eh[l][0] = tab[(u0 ^ u1m) & MASKU];
    eh[l][1] = tab[(u0 ^ (u1m + P1U)) & MASKU];
    eh[l][2] = tab[((u0 + 1u) ^ u1m) & MASKU];
    eh[l][3] = tab[((u0 + 1u) ^ (u1m + P1U)) & MASKU];
  }

  float feat[32];
#pragma unroll
  for (int l = 0; l < 12; ++l) {
    float w0 = w0a[l], w1 = w1a[l];
    float omw0 = 1.0f - w0, omw1 = 1.0f - w1;
    float c0x = lo[l].x * omw1 + lo[l].z * w1;
    float c0y = lo[l].y * omw1 + lo[l].w * w1;
    float c1x = hi[l].x * omw1 + hi[l].z * w1;
    float c1y = hi[l].y * omw1 + hi[l].w * w1;
    feat[2 * l]     = c0x * omw0 + c1x * w0;
    feat[2 * l + 1] = c0y * omw0 + c1y * w0;
  }
#pragma unroll
  for (int l = 0; l < 4; ++l) {
    float w0 = w0a[12 + l], w1 = w1a[12 + l];
    float omw0 = 1.0f - w0, omw1 = 1.0f - w1;
    float c0x = eh[l][0].x * omw1 + eh[l][1].x * w1;
    float c0y = eh[l][0].y * omw1 + eh[l][1].y * w1;
    float c1x = eh[l][2].x * omw1 + eh[l][3].x * w1;
    float c1y = eh[l][2].y * omw1 + eh[l][3].y * w1;
    feat[24 + 2 * l]     = c0x * omw0 + c1x * w0;
    feat[24 + 2 * l + 1] = c0y * omw0 + c1y * w0;
  }

  float4* o = reinterpret_cast<float4*>(out) + (size_t)orig * 8;
#pragma unroll
  for (int j = 0; j < 8; ++j) {
    o[j] = make_float4(feat[4 * j], feat[4 * j + 1], feat[4 * j + 2], feat[4 * j + 3]);
  }
}

// ---------------- per-XCD partitioned capacity-bin sort ---------------------

// child index: 4 children of each 32-px parent are contiguous
__device__ __forceinline__ int child_of(float2 xv) {
  int bx = min((int)(xv.x * 0.0625f), CBINS_X - 1);   // 16-px coords
  int by = min((int)(xv.y * 0.0625f), CBINS_X - 1);
  int parent = ((bx >> 1) << 6) + (by >> 1);          // 64x64 parents
  int quad = ((bx & 1) << 1) + (by & 1);
  return (parent << 2) + quad;
}

__global__ __launch_bounds__(256) void scatter_px(
    const float2* __restrict__ xs, int* __restrict__ cnt,
    float4* __restrict__ recs,
    int* __restrict__ ovf, int* __restrict__ ovf_cnt, int B) {
  int p = blockIdx.x * 256 + threadIdx.x;
  if (p >= B) return;
  int part = blockIdx.x & 7;              // this block's XCD (round-robin map)
  float2 xv = xs[p];
  int pc = part * NCHILD + child_of(xv);  // (xcd, child) composite
  int pos = atomicAdd(&cnt[pc], 1);       // counter line local to this XCD
  if (pos < CAPX) {
    recs[(size_t)pc * CAPX + pos] =       // record line local to this XCD
        make_float4(xv.x, xv.y, __int_as_float(p), 0.0f);
  } else {
    int o = atomicAdd(ovf_cnt, 1);
    ovf[o] = p;  // ovf capacity == B: can never overflow
  }
}

// main: block = one 32-px parent; compact over 32 (child,part) bins; each
// thread processes up to 4 compacted points (mean 2)
__global__ __launch_bounds__(256, 2) void hashenc_par(
    const float4* __restrict__ recs, const int* __restrict__ cnt,
    const float* __restrict__ tables, float* __restrict__ out) {
  __shared__ int pre[33];
  __shared__ short bmap[1024];
  int bid = blockIdx.x;
  int nb = gridDim.x;                     // 4096, divisible by 8
  int chunk = nb >> 3;                    // 512 parents per XCD slab
  int par = (bid & 7) * chunk + (bid >> 3);   // XCD k owns slab k (spatial)

  if (threadIdx.x == 0) {
    int s = 0;
    pre[0] = 0;
#pragma unroll
    for (int b = 0; b < 32; ++b) {        // b = c*8 + k
      int c = b >> 3, k = b & 7;
      s += min(cnt[k * NCHILD + (par * 4 + c)], CAPX);
      pre[b + 1] = s;
    }
  }
  __syncthreads();
  if (threadIdx.x < 32) {                 // fill slot->bin map (<=32 iters)
    int b = threadIdx.x;
    int s = pre[b], e = pre[b + 1];
    for (int j = s; j < e; ++j) bmap[j] = (short)b;
  }
  __syncthreads();

  int total = pre[32];
#pragma unroll
  for (int rep = 0; rep < 4; ++rep) {
    int idx = threadIdx.x + rep * 256;
    if (idx < total) {
      int b = bmap[idx];
      int c = b >> 3, k = b & 7;
      int j = idx - pre[b];
      float4 r = recs[((size_t)(k * NCHILD + par * 4 + c)) * CAPX + j];
      embed_point(make_float2(r.x, r.y), __float_as_int(r.z), tables, out);
    }
  }
}

__global__ __launch_bounds__(256) void ovf_kernel(
    const float2* __restrict__ xs, const int* __restrict__ ovf,
    const int* __restrict__ ovf_cnt, const float* __restrict__ tables,
    float* __restrict__ out) {
  int n = *ovf_cnt;
  for (int i = blockIdx.x * 256 + threadIdx.x; i < n; i += gridDim.x * 256) {
    int p = ovf[i];
    embed_point(xs[p], p, tables, out);
  }
}

// ---------------- unsorted fallback -----------------------------------------

__global__ __launch_bounds__(256, 2) void hashenc_plain(
    const float2* __restrict__ xs, const float* __restrict__ tables,
    float* __restrict__ out, int B) {
  int p = blockIdx.x * 256 + threadIdx.x;
  if (p >= B) return;
  embed_point(xs[p], p, tables, out);
}

// ---------------- launch ----------------------------------------------------

extern "C" void kernel_launch(void* const* d_in, const int* in_sizes, int n_in,
                              void* d_out, int out_size, void* d_ws, size_t ws_size,
                              hipStream_t stream) {
  const float2* xs = (const float2*)d_in[0];
  const float* tables = (const float*)d_in[1];
  float* out = (float*)d_out;
  int B = in_sizes[0] / 2;
  int blocks = (B + 255) / 256;
  char* ws = (char*)d_ws;

  // layout: recs (16B*SLOTS = 67MB) | ovf (4B*B) | cnt (4B*8*NCHILD = 512KB)
  //         | ovf_cnt (+pad)
  size_t c_recs = 0;
  size_t c_ovf = c_recs + (size_t)SLOTS * 16;
  size_t c_cnt = c_ovf + (size_t)B * 4;
  size_t c_ocnt = c_cnt + (size_t)XPART * NCHILD * 4;
  size_t need = c_ocnt + 64;

  bool grid_ok = (blocks & 7) == 0;
  if (grid_ok && ws_size >= need) {
    float4* recs = (float4*)(ws + c_recs);
    int* ovf = (int*)(ws + c_ovf);
    int* cnt = (int*)(ws + c_cnt);
    int* ovf_cnt = (int*)(ws + c_ocnt);
    (void)hipMemsetAsync(cnt, 0, (size_t)XPART * NCHILD * 4 + 64, stream);
    hipLaunchKernelGGL(scatter_px, dim3(blocks), dim3(256), 0, stream,
                       xs, cnt, recs, ovf, ovf_cnt, B);
    hipLaunchKernelGGL(hashenc_par, dim3(NPAR), dim3(256), 0, stream,
                       recs, cnt, tables, out);
    hipLaunchKernelGGL(ovf_kernel, dim3(32), dim3(256), 0, stream,
                       xs, ovf, ovf_cnt, tables, out);
  } else {
    hipLaunchKernelGGL(hashenc_plain, dim3(blocks), dim3(256), 0, stream,
                       xs, tables, out, B);
  }
}